// Round 2
// baseline (455.029 us; speedup 1.0000x reference)
//
#include <hip/hip_runtime.h>

// Decoder: 12 sequential steps of {attention over 12 enc timesteps, GRU cell, linear->scalar, feedback}.
// B=65536 batch elements independent -> block owns 16 batch elems, 16 lanes per b, 4 dims per lane.
// R7: R6's MFMA fold, with sum16 reverted to the update_dpp intrinsic.
//  - R6 FAILED (absmax 34.75): inline-asm v_add_f32_dpp has a VALU-write -> DPP-read hazard
//    (2 wait states) that the compiler can't see inside INLINEASM; reads were stale. The
//    update_dpp intrinsic path is hazard-handled (and GCNDPPCombine fuses it to v_add_f32_dpp
//    where legal anyway).
//  - Kept from R6: input-side GRU (Wih*lst + b_ih) and ALL biases folded into the MFMA as a
//    3rd k-chunk: A = [h(64) | l0,l1,l2,1 | 0-pad] staged hi/lo (row stride 96 halves),
//    B columns = 256: [r-combined | z-combined | n_hidden | n_input], biases ride k-row 67.
//    Removes ~26 pk-ops/step/lane of gate pre-activation AND the Wih(36)+bias(16) register
//    demand that forced AGPR shuttling. MFMA 18->25/wave/step (pipe at 10% util has headroom).

#define TT 12     // T_IN == T_OUT == 12
#define BB 65536
#define HH 64

typedef _Float16 half8 __attribute__((ext_vector_type(8)));
typedef _Float16 half4 __attribute__((ext_vector_type(4)));
typedef float    f32x4 __attribute__((ext_vector_type(4)));
typedef float    f32x2 __attribute__((ext_vector_type(2)));

#define L2E 1.44269504088896f

__device__ __forceinline__ float ex2(float x){ return __builtin_amdgcn_exp2f(x); }
__device__ __forceinline__ float sigm(float x){ return 1.0f/(1.0f + ex2(-L2E*x)); }
__device__ __forceinline__ float tanh_(float x){ return 1.0f - 2.0f/(ex2(2.0f*L2E*x)+1.0f); }

// DPP row_ror rotate-reduce within the 16-lane row: after ror:1,2,4,8 every lane holds the row sum.
// update_dpp intrinsic => compiler handles DPP hazards and fuses mov_dpp+add where legal.
template<int N>
__device__ __forceinline__ float ror_add(float x){
    int s = __builtin_amdgcn_update_dpp(0, __float_as_int(x), 0x120+N, 0xF, 0xF, false);
    return x + __int_as_float(s);
}
__device__ __forceinline__ float sum16(float x){
    x = ror_add<1>(x); x = ror_add<2>(x); x = ror_add<4>(x); x = ror_add<8>(x);
    return x;
}

__device__ __forceinline__ float max3f(float a, float b, float c){
    return fmaxf(fmaxf(a,b),c);   // clang folds to v_max3_f32
}

#define MFMA16(A,B,C) __builtin_amdgcn_mfma_f32_16x16x32_f16(A,B,C,0,0,0)

__global__ __launch_bounds__(256, 2)
void decoder_kernel(const float* __restrict__ enc,    // (12,B,64)
                    const float* __restrict__ hid0,   // (B,64)
                    const float* __restrict__ last0,  // (B,3)
                    const float* __restrict__ Wih,    // (192,3)
                    const float* __restrict__ Whh,    // (192,64)
                    const float* __restrict__ bih,    // (192)
                    const float* __restrict__ bhh,    // (192)
                    const float* __restrict__ Wlin,   // (64)
                    const float* __restrict__ blin,   // (1)
                    float* __restrict__ out)          // (B,12)
{
    // A-staging rows: [h(64) | lst(4) | zero-pad(28)] hi + lo residual. stride 96 halves (192B).
    __shared__ __align__(16) _Float16 sHi[16*96];
    __shared__ __align__(16) _Float16 sLo[16*96];
    // Gate pre-activations: 16 batch rows x [R(64) | Z(64) | NH(64) | NI(64)], stride 260 floats.
    __shared__ __align__(16) float    sGh[16*260];

    const int tid  = threadIdx.x;
    const int wv   = tid >> 6;        // wave 0..3
    const int lane = tid & 63;
    const int q    = lane & 15;       // dim group / MFMA n or m index
    const int quad = lane >> 4;       // which batch elem of this wave (attn phase) / k-subchunk (MFMA)
    const int m    = wv*4 + quad;     // batch row within block, 0..15
    const size_t b = (size_t)blockIdx.x*16 + m;
    const int jq   = wv*16 + q;       // this lane's output column within each 64-col gate region

    // one-time zero of the pad region (halves 68..95 of each row) so chunk-2 A-frags of
    // quads 1..3 read zeros. Visibility guaranteed by the step-0 __syncthreads.
    for (int i = tid; i < 16*96; i += 256){
        if ((i % 96) >= 68){ sHi[i] = (_Float16)0; sLo[i] = (_Float16)0; }
    }

    // ---- one-time loads (register-resident) ----
    f32x4 e4[TT];
    #pragma unroll
    for (int t=0;t<TT;++t)
        e4[t] = *(const f32x4*)(enc + ((size_t)t*BB + b)*HH + 4*q);

    f32x4 h = *(const f32x4*)(hid0 + b*HH + 4*q);
    float l0 = last0[b*3+0], l1 = last0[b*3+1], l2 = last0[b*3+2];
    float bl = blin[0];
    f32x4 wl = *(const f32x4*)(Wlin + 4*q);

    // W_hh^T B-fragments, hi/lo fp16 split (k-chunks 0,1), per gate region.
    // B-frag layout: n = lane&15 (col jq), k = kc*32 + quad*8 + jj.
    half8 bR0h,bR0l,bR1h,bR1l, bZ0h,bZ0l,bZ1h,bZ1l, bN0h,bN0l,bN1h,bN1l;
    {
        #pragma unroll
        for (int g=0; g<3; ++g){
            int row = g*64 + jq;      // Whh row: r / z / n
            #pragma unroll
            for (int kc=0; kc<2; ++kc){
                const float* src = Whh + row*64 + kc*32 + quad*8;
                half8 vh, vl;
                #pragma unroll
                for (int jj=0;jj<8;++jj){
                    float w = src[jj];
                    _Float16 whi = (_Float16)w;
                    vh[jj] = whi;
                    vl[jj] = (_Float16)(w - (float)whi);
                }
                if (g==0){ if(kc==0){bR0h=vh;bR0l=vl;} else {bR1h=vh;bR1l=vl;} }
                else if (g==1){ if(kc==0){bZ0h=vh;bZ0l=vl;} else {bZ1h=vh;bZ1l=vl;} }
                else { if(kc==0){bN0h=vh;bN0l=vl;} else {bN1h=vh;bN1l=vl;} }
            }
        }
    }
    // chunk-2 B-frags: rows k=64..67 hold [Wih col0..2 | bias]; only quad==0 lanes nonzero.
    half8 bR2h, bZ2h, bN2h, bI2h;
    #pragma unroll
    for (int jj=0;jj<8;++jj){ bR2h[jj]=(_Float16)0; bZ2h[jj]=(_Float16)0; bN2h[jj]=(_Float16)0; bI2h[jj]=(_Float16)0; }
    if (quad == 0){
        #pragma unroll
        for (int jj=0;jj<3;++jj){
            bR2h[jj] = (_Float16)Wih[(      jq)*3 + jj];
            bZ2h[jj] = (_Float16)Wih[( 64 + jq)*3 + jj];
            bI2h[jj] = (_Float16)Wih[(128 + jq)*3 + jj];
        }
        bR2h[3] = (_Float16)(bih[      jq] + bhh[      jq]);
        bZ2h[3] = (_Float16)(bih[ 64 + jq] + bhh[ 64 + jq]);
        bN2h[3] = (_Float16)(bhh[128 + jq]);
        bI2h[3] = (_Float16)(bih[128 + jq]);
    }

    // ---- 12 sequential decoder steps ----
    for (int s=0;s<TT;++s){
        // attention logits: packed dot + DPP rotate-reduce
        float a[TT];
        #pragma unroll
        for (int t=0;t<TT;++t){
            f32x2 p2 = e4[t].xy * h.xy;
            p2 += e4[t].zw * h.zw;
            a[t] = sum16(p2.x + p2.y);
        }
        // max via v_max3 triples
        float m0 = max3f(a[0],a[1],a[2]),  m1 = max3f(a[3],a[4],a[5]);
        float m2 = max3f(a[6],a[7],a[8]),  m3 = max3f(a[9],a[10],a[11]);
        float mx = fmaxf(max3f(m0,m1,m2), m3);
        float nm = -mx*L2E;
        #pragma unroll
        for (int t=0;t<TT;++t) a[t] = ex2(__builtin_fmaf(a[t], L2E, nm));
        // sum (tree)
        float s01=a[0]+a[1], s23=a[2]+a[3], s45=a[4]+a[5], s67=a[6]+a[7], s89=a[8]+a[9], sab=a[10]+a[11];
        float ss = ((s01+s23)+(s45+s67)) + (s89+sab);
        float inv = 1.0f/ss;
        // context: dual f32x4 accumulators (v_pk_fma_f32), then h += ctx*inv
        f32x4 ctxA = {0.f,0.f,0.f,0.f}, ctxB = {0.f,0.f,0.f,0.f};
        #pragma unroll
        for (int t=0;t<TT;t+=2){
            ctxA += e4[t]   * (f32x4)(a[t]);
            ctxB += e4[t+1] * (f32x4)(a[t+1]);
        }
        h += (ctxA + ctxB) * (f32x4)(inv);

        // stage h into LDS as fp16 hi + lo residual (~2^-22 combined)
        half4 hhi, hlo;
        #pragma unroll
        for (int j=0;j<4;++j){
            _Float16 hh = (_Float16)h[j];
            hhi[j] = hh;
            hlo[j] = (_Float16)(h[j] - (float)hh);
        }
        *(half4*)&sHi[m*96 + 4*q] = hhi;
        *(half4*)&sLo[m*96 + 4*q] = hlo;
        // stage lst (+the bias lane's 1.0) at halves 64..67
        if (q == 0){
            _Float16 a0=(_Float16)l0, a1=(_Float16)l1, a2=(_Float16)l2;
            half4 th = {a0, a1, a2, (_Float16)1.0f};
            half4 tl = {(_Float16)(l0-(float)a0), (_Float16)(l1-(float)a1),
                        (_Float16)(l2-(float)a2), (_Float16)0.0f};
            *(half4*)&sHi[m*96 + 64] = th;
            *(half4*)&sLo[m*96 + 64] = tl;
        }
        __syncthreads();

        // MFMA: pre-acts for 16 batch rows x 256 cols [R|Z|NH|NI], k = [h(64) | lst,1 | pad].
        // A-frag: row = lane&15 (=q), k = kc*32 + quad*8 + jj.
        half8 ahi0 = *(half8*)&sHi[q*96 +  0 + quad*8];
        half8 ahi1 = *(half8*)&sHi[q*96 + 32 + quad*8];
        half8 ahi2 = *(half8*)&sHi[q*96 + 64 + quad*8];
        half8 alo0 = *(half8*)&sLo[q*96 +  0 + quad*8];
        half8 alo1 = *(half8*)&sLo[q*96 + 32 + quad*8];
        half8 alo2 = *(half8*)&sLo[q*96 + 64 + quad*8];

        // R region (cols 0..63): hidden hi/lo 3-term + input/bias chunk (hi + lo contributions)
        {
            f32x4 acc = {0.f,0.f,0.f,0.f};
            acc = MFMA16(ahi0,bR0h,acc); acc = MFMA16(ahi1,bR1h,acc);
            acc = MFMA16(ahi0,bR0l,acc); acc = MFMA16(ahi1,bR1l,acc);
            acc = MFMA16(alo0,bR0h,acc); acc = MFMA16(alo1,bR1h,acc);
            acc = MFMA16(ahi2,bR2h,acc); acc = MFMA16(alo2,bR2h,acc);
            #pragma unroll
            for (int r=0;r<4;++r) sGh[(quad*4+r)*260 +   0 + jq] = acc[r];
        }
        // Z region (cols 64..127)
        {
            f32x4 acc = {0.f,0.f,0.f,0.f};
            acc = MFMA16(ahi0,bZ0h,acc); acc = MFMA16(ahi1,bZ1h,acc);
            acc = MFMA16(ahi0,bZ0l,acc); acc = MFMA16(ahi1,bZ1l,acc);
            acc = MFMA16(alo0,bZ0h,acc); acc = MFMA16(alo1,bZ1h,acc);
            acc = MFMA16(ahi2,bZ2h,acc); acc = MFMA16(alo2,bZ2h,acc);
            #pragma unroll
            for (int r=0;r<4;++r) sGh[(quad*4+r)*260 +  64 + jq] = acc[r];
        }
        // NH region (cols 128..191): hidden side + b_hh_n (rides ahi2's 1.0 lane)
        {
            f32x4 acc = {0.f,0.f,0.f,0.f};
            acc = MFMA16(ahi0,bN0h,acc); acc = MFMA16(ahi1,bN1h,acc);
            acc = MFMA16(ahi0,bN0l,acc); acc = MFMA16(ahi1,bN1l,acc);
            acc = MFMA16(alo0,bN0h,acc); acc = MFMA16(alo1,bN1h,acc);
            acc = MFMA16(ahi2,bN2h,acc);
            #pragma unroll
            for (int r=0;r<4;++r) sGh[(quad*4+r)*260 + 128 + jq] = acc[r];
        }
        // NI region (cols 192..255): input side only (Wih_n * lst + b_ih_n)
        {
            f32x4 acc = {0.f,0.f,0.f,0.f};
            acc = MFMA16(ahi2,bI2h,acc); acc = MFMA16(alo2,bI2h,acc);
            #pragma unroll
            for (int r=0;r<4;++r) sGh[(quad*4+r)*260 + 192 + jq] = acc[r];
        }
        __syncthreads();

        // gates: r=sig(R), z=sig(Z), n=tanh(NI + r*NH), h'=(1-z)n+z*h  (pre-acts incl. biases)
        f32x4 gR  = *(f32x4*)&sGh[m*260 +   0 + 4*q];
        f32x4 gZ  = *(f32x4*)&sGh[m*260 +  64 + 4*q];
        f32x4 gNH = *(f32x4*)&sGh[m*260 + 128 + 4*q];
        f32x4 gNI = *(f32x4*)&sGh[m*260 + 192 + 4*q];

        float o = 0.f;
        #pragma unroll
        for (int j=0;j<4;++j){
            float r = sigm(gR[j]);
            float z = sigm(gZ[j]);
            float n = tanh_(gNI[j] + r*gNH[j]);
            float hn = (1.f - z)*n + z*h[j];
            h[j] = hn;
            o += hn * wl[j];
        }
        // out = h' . W_lin + b_lin, DPP rotate-reduce over 16-lane group
        o = sum16(o) + bl;
        if (q == 0) out[b*TT + s] = o;
        // last = [out, last[0], last[1]]
        l2 = l1; l1 = l0; l0 = o;
    }
}

extern "C" void kernel_launch(void* const* d_in, const int* in_sizes, int n_in,
                              void* d_out, int out_size, void* d_ws, size_t ws_size,
                              hipStream_t stream)
{
    const float* enc  = (const float*)d_in[0];
    const float* hid0 = (const float*)d_in[1];
    const float* lst  = (const float*)d_in[2];
    const float* Wih  = (const float*)d_in[3];
    const float* Whh  = (const float*)d_in[4];
    const float* bih  = (const float*)d_in[5];
    const float* bhh  = (const float*)d_in[6];
    const float* Wlin = (const float*)d_in[7];
    const float* blin = (const float*)d_in[8];
    decoder_kernel<<<BB/16, 256, 0, stream>>>(enc, hid0, lst, Wih, Whh, bih, bhh,
                                              Wlin, blin, (float*)d_out);
}